// Round 3
// baseline (243.287 us; speedup 1.0000x reference)
//
#include <hip/hip_runtime.h>
#include <hip/hip_fp16.h>
#include <math.h>

// ---------------------------------------------------------------------------
// GCN: h1 = relu(Dinv (A+I) Dinv (x@W1) + b1); h2 = relu(Dinv (A+I) Dinv (h1@W2) + b2)
// score = (h2@aw+ab)*sigmoid(h2@mw+mb); out[g] = out_b + sum_v score*(h2@ow)
// R10 sharded bins + counting sort ->277. R12 gather_gemm fusion.
// R13 NEUTRAL (GEMM-loop change): gemm_bin not GEMM-bound.
// R14: fp16 P/Q (fp32 accum) -> gathers -47us (238 total); x8-batched
//      binning REGRESSED 65->73us -> binning is THROUGHPUT-bound on 1M
//      device-scope atomicAdd RMWs at the coherent point (+1M random 4B
//      gbuf scatters), not latency-bound.
// R15 (this): block-aggregated two-pass binning: 64 blocks; LDS histogram
//      (1563 buckets) -> ONE global atomicAdd per (block,bucket) = 100K
//      device atomics (10x fewer) reserving contiguous runs -> re-read
//      chunk (L2-hot) + LDS-cursor scatter = contiguous gbuf runs.
//      sort_kernel: single bcnt[b] count, no SEG compaction.
// ---------------------------------------------------------------------------

#define NB 64               // nodes per bucket (bucket = v >> 6)
#define SLOTS 1280          // slots per bucket; mean 640, sd ~25 (25 sigma)
#define BIN_BLOCKS 64
#define MAXBUCK 2048        // LDS histogram capacity (N <= 131072)

__device__ __forceinline__ void h8_set(float* a, const int4 w) {
    const __half2* h = (const __half2*)&w;
    float2 t0 = __half22float2(h[0]);
    float2 t1 = __half22float2(h[1]);
    float2 t2 = __half22float2(h[2]);
    float2 t3 = __half22float2(h[3]);
    a[0] = t0.x; a[1] = t0.y; a[2] = t1.x; a[3] = t1.y;
    a[4] = t2.x; a[5] = t2.y; a[6] = t3.x; a[7] = t3.y;
}
__device__ __forceinline__ void h8_acc(float* a, const int4 w) {
    const __half2* h = (const __half2*)&w;
    float2 t0 = __half22float2(h[0]);
    float2 t1 = __half22float2(h[1]);
    float2 t2 = __half22float2(h[2]);
    float2 t3 = __half22float2(h[3]);
    a[0] += t0.x; a[1] += t0.y; a[2] += t1.x; a[3] += t1.y;
    a[4] += t2.x; a[5] += t2.y; a[6] += t3.x; a[7] += t3.y;
}

// ---- fused: blocks [0,BIN_BLOCKS) bin edges (+ init out); rest P = x@W1 ----
__global__ __launch_bounds__(256) void gemm_bin_kernel(
    const float* __restrict__ X, const float* __restrict__ W,
    __half* __restrict__ P, int N, int K,
    const int* __restrict__ row, const int* __restrict__ col,
    int* __restrict__ bcnt, int* __restrict__ gbuf, int E,
    float* __restrict__ out, const float* __restrict__ out_b, int G) {
    __shared__ float Wl[32 * 64];    // 8 KB
    __shared__ float xs[32 * 132];   // 16.9 KB TRANSPOSED x tile [k][node]

    if (blockIdx.x < BIN_BLOCKS) {
        // two-pass block-aggregated binning (LDS hist reuses the GEMM LDS)
        int* lhist = (int*)Wl;       // MAXBUCK ints = 8 KB
        const int tid = threadIdx.x;
        const int nbuck = (N + NB - 1) >> 6;
        int t = blockIdx.x * 256 + tid;
        if (t < G) out[t] = out_b[0];
        for (int i = tid; i < nbuck; i += 256) lhist[i] = 0;
        __syncthreads();
        const int chunk = (E + BIN_BLOCKS - 1) / BIN_BLOCKS;
        const int e0 = blockIdx.x * chunk;
        const int e1 = (e0 + chunk < E) ? e0 + chunk : E;
        // pass 1: LDS histogram of this chunk's buckets
        for (int e = e0 + tid; e < e1; e += 256)
            atomicAdd(&lhist[col[e] >> 6], 1);
        __syncthreads();
        // reserve contiguous runs: one device atomic per non-empty bucket
        for (int b = tid; b < nbuck; b += 256) {
            int cnt = lhist[b];
            lhist[b] = (cnt > 0) ? atomicAdd(&bcnt[b], cnt) : 0;
        }
        __syncthreads();
        // pass 2: re-read chunk (L2-hot), LDS-cursor scatter into runs
        for (int e = e0 + tid; e < e1; e += 256) {
            int c = col[e];
            int b = c >> 6;
            int p = atomicAdd(&lhist[b], 1);
            if (p < SLOTS) gbuf[b * SLOTS + p] = row[e] | ((c & 63) << 17);
        }
        return;  // uniform per-block branch
    }

    const int tid = threadIdx.x;
    const int cg = tid & 7;        // 8 col-groups x 8 cols
    const int ng = tid >> 3;       // 32 node-groups x 4 rows = 128 nodes
    const int node0 = (blockIdx.x - BIN_BLOCKS) * 128;

    float acc[4][8];
#pragma unroll
    for (int r = 0; r < 4; r++)
#pragma unroll
        for (int j = 0; j < 8; j++) acc[r][j] = 0.0f;

    for (int k0 = 0; k0 < K; k0 += 32) {   // runtime loop: keeps VGPR bounded
        const float4* Wg = (const float4*)(W + (size_t)k0 * 64);
#pragma unroll
        for (int f = tid; f < 512; f += 256) ((float4*)Wl)[f] = Wg[f];
        {
            int rrow = tid >> 1;
            int q0 = (tid & 1) * 16;
            int node = node0 + rrow;
            const float* Xr = X + (size_t)node * K + k0 + q0;
#pragma unroll
            for (int q = 0; q < 4; q++) {
                float4 v = make_float4(0.f, 0.f, 0.f, 0.f);
                if (node < N) v = *(const float4*)(Xr + 4 * q);
                int kb = q0 + 4 * q;           // transposed store: xs[k][node]
                xs[(kb + 0) * 132 + rrow] = v.x;
                xs[(kb + 1) * 132 + rrow] = v.y;
                xs[(kb + 2) * 132 + rrow] = v.z;
                xs[(kb + 3) * 132 + rrow] = v.w;
            }
        }
        __syncthreads();
#pragma unroll
        for (int kk = 0; kk < 32; kk++) {
            float4 xv = *(const float4*)&xs[kk * 132 + ng * 4];
            const float* wr = &Wl[kk * 64 + cg * 8];
            float4 w0 = *(const float4*)(wr + 0);
            float4 w1 = *(const float4*)(wr + 4);
#pragma unroll
            for (int r = 0; r < 4; r++) {
                float xr = (r == 0) ? xv.x : (r == 1) ? xv.y : (r == 2) ? xv.z : xv.w;
                acc[r][0] = fmaf(xr, w0.x, acc[r][0]);
                acc[r][1] = fmaf(xr, w0.y, acc[r][1]);
                acc[r][2] = fmaf(xr, w0.z, acc[r][2]);
                acc[r][3] = fmaf(xr, w0.w, acc[r][3]);
                acc[r][4] = fmaf(xr, w1.x, acc[r][4]);
                acc[r][5] = fmaf(xr, w1.y, acc[r][5]);
                acc[r][6] = fmaf(xr, w1.z, acc[r][6]);
                acc[r][7] = fmaf(xr, w1.w, acc[r][7]);
            }
        }
        __syncthreads();
    }

#pragma unroll
    for (int r = 0; r < 4; r++) {
        int node = node0 + ng * 4 + r;
        if (node < N) {
            __half2 hh[4];
            hh[0] = __floats2half2_rn(acc[r][0], acc[r][1]);
            hh[1] = __floats2half2_rn(acc[r][2], acc[r][3]);
            hh[2] = __floats2half2_rn(acc[r][4], acc[r][5]);
            hh[3] = __floats2half2_rn(acc[r][6], acc[r][7]);
            ((int4*)(P + (size_t)node * 64))[cg] = *(int4*)hh;
        }
    }
}

// ---- per-bucket LDS counting sort -> dense csr + startcnt + dinv,
//      then pre-scale P' = dinv * P (fp16 rows, coalesced) ----
__global__ __launch_bounds__(256) void sort_kernel(
    const int* __restrict__ bcnt, const int* __restrict__ gbuf,
    int* __restrict__ csr, int* __restrict__ startcnt,
    float* __restrict__ dinv, __half* __restrict__ P, int N) {
    __shared__ int s_tot;
    __shared__ int ebuf[SLOTS];     // 5 KB
    __shared__ int lcnt[NB], lcur[NB];
    __shared__ float sdinv[NB];
    const int tid = threadIdx.x;
    const int b = blockIdx.x;
    const int base = b * SLOTS;

    if (tid == 0) {
        int c = bcnt[b];
        s_tot = c < SLOTS ? c : SLOTS;
    }
    if (tid < NB) lcnt[tid] = 0;
    __syncthreads();
    const int tot = s_tot;
    // load runs + histogram destination nodes
    for (int idx = tid; idx < tot; idx += 256) {
        int w = gbuf[base + idx];
        ebuf[idx] = w;
        atomicAdd(&lcnt[(w >> 17) & 63], 1);
    }
    __syncthreads();
    if (tid < NB) {
        int cntv = lcnt[tid];
        int rnd = (cntv + 3) & ~3;          // 4-aligned region for int4 loads
        int val = rnd;
#pragma unroll
        for (int off = 1; off < 64; off <<= 1) {
            int n = __shfl_up(val, off, 64);
            if (tid >= off) val += n;
        }
        int st = val - rnd;
        lcur[tid] = st;
        float d = rsqrtf(1.0f + (float)cntv);
        sdinv[tid] = d;
        int v = b * NB + tid;
        if (v < N) {
            dinv[v] = d;
            int cc = cntv < 127 ? cntv : 127;
            startcnt[v] = ((base + st) << 7) | cc;   // base+st < 2M -> fits
        }
    }
    __syncthreads();
    for (int idx = tid; idx < tot; idx += 256) {
        int w = ebuf[idx];
        int vl = (w >> 17) & 63;
        int pp = atomicAdd(&lcur[vl], 1);
        csr[base + pp] = w & 131071;
    }
    // pre-scale this bucket's fp16 P rows: P'[v] = dinv[v] * P[v]
    for (int idx = tid; idx < NB * 8; idx += 256) {   // 8x16B chunks per row
        int r = idx >> 3;
        int v = b * NB + r;
        if (v < N) {
            float d = sdinv[r];
            int4* pp = (int4*)(P + (size_t)v * 64) + (idx & 7);
            int4 t = *pp;
            __half2* hp = (__half2*)&t;
#pragma unroll
            for (int q = 0; q < 4; q++) {
                float2 f = __half22float2(hp[q]);
                hp[q] = __floats2half2_rn(f.x * d, f.y * d);
            }
            *pp = t;
        }
    }
}

// ---- fused layer-1 aggregate + layer-2 GEMM ----
// Block = 64 nodes (one bucket). Phase 1: gather fp16 P' rows (8 lanes/row,
// int4/lane) -> fp32 accum -> h1 tile in LDS. Phase 2: Q' = dinv*(h1@W2),
// 2x8 register tile, RUNTIME kk-loop; Q stored fp16.
__global__ __launch_bounds__(256) void gather_gemm_kernel(
    const __half* __restrict__ P, const int* __restrict__ csr,
    const int* __restrict__ startcnt, const float* __restrict__ dinv,
    const float* __restrict__ b1, const float* __restrict__ W2,
    __half* __restrict__ Q, int N) {
    __shared__ float hs[64 * 65];   // 16.6 KB h1 tile
    __shared__ float Wl[64 * 64];   // 16 KB full W2
    const int tid = threadIdx.x;
    const int v0 = blockIdx.x * 64;
    const int vend = (v0 + 64 < N) ? v0 + 64 : N;
    const int p = tid & 7;          // 8 lanes per row (128B fp16 row)

    for (int f = tid; f < 1024; f += 256)
        ((float4*)Wl)[f] = ((const float4*)W2)[f];

    const float4 bb0 = ((const float4*)b1)[2 * p];
    const float4 bb1 = ((const float4*)b1)[2 * p + 1];
    for (int v = v0 + (tid >> 3); v < vend; v += 32) {
        int pack = startcnt[v];
        int st = pack >> 7;           // 4-aligned
        int c = pack & 127;
        float dv = dinv[v];
        float a[8];
        h8_set(a, ((const int4*)(P + (size_t)v * 64))[p]);   // self: P' has dv
        for (int i = 0; i < c; i += 8) {
            int4 ua = *(const int4*)(csr + st + i);      // pad slots = 0, safe
            int4 ub = *(const int4*)(csr + st + i + 4);
            int4 m0 = ((const int4*)(P + (size_t)ua.x * 64))[p];
            int4 m1 = ((const int4*)(P + (size_t)ua.y * 64))[p];
            int4 m2 = ((const int4*)(P + (size_t)ua.z * 64))[p];
            int4 m3 = ((const int4*)(P + (size_t)ua.w * 64))[p];
            int4 m4 = ((const int4*)(P + (size_t)ub.x * 64))[p];
            int4 m5 = ((const int4*)(P + (size_t)ub.y * 64))[p];
            int4 m6 = ((const int4*)(P + (size_t)ub.z * 64))[p];
            int4 m7 = ((const int4*)(P + (size_t)ub.w * 64))[p];
            h8_acc(a, m0);
            if (i + 1 < c) h8_acc(a, m1);
            if (i + 2 < c) h8_acc(a, m2);
            if (i + 3 < c) h8_acc(a, m3);
            if (i + 4 < c) h8_acc(a, m4);
            if (i + 5 < c) h8_acc(a, m5);
            if (i + 6 < c) h8_acc(a, m6);
            if (i + 7 < c) h8_acc(a, m7);
        }
        float* hd = &hs[(v - v0) * 65 + p * 8];
        hd[0] = fmaxf(fmaf(a[0], dv, bb0.x), 0.f);
        hd[1] = fmaxf(fmaf(a[1], dv, bb0.y), 0.f);
        hd[2] = fmaxf(fmaf(a[2], dv, bb0.z), 0.f);
        hd[3] = fmaxf(fmaf(a[3], dv, bb0.w), 0.f);
        hd[4] = fmaxf(fmaf(a[4], dv, bb1.x), 0.f);
        hd[5] = fmaxf(fmaf(a[5], dv, bb1.y), 0.f);
        hd[6] = fmaxf(fmaf(a[6], dv, bb1.z), 0.f);
        hd[7] = fmaxf(fmaf(a[7], dv, bb1.w), 0.f);
    }
    __syncthreads();

    // Phase 2: Q'[v] = dinv * (hs @ W2); 2 rows x 8 cols per thread
    const int cg = tid & 7;
    const int n0 = tid >> 3;       // 0..31, 2 rows each
    float acc2[2][8];
#pragma unroll
    for (int r = 0; r < 2; r++)
#pragma unroll
        for (int j = 0; j < 8; j++) acc2[r][j] = 0.0f;
    for (int kk = 0; kk < 64; kk++) {     // RUNTIME loop (R6/R8 lesson)
        float x0 = hs[(n0 * 2 + 0) * 65 + kk];
        float x1 = hs[(n0 * 2 + 1) * 65 + kk];
        const float* wr = &Wl[kk * 64 + cg * 8];
        float4 w0 = *(const float4*)(wr + 0);
        float4 w1 = *(const float4*)(wr + 4);
        acc2[0][0] = fmaf(x0, w0.x, acc2[0][0]);
        acc2[0][1] = fmaf(x0, w0.y, acc2[0][1]);
        acc2[0][2] = fmaf(x0, w0.z, acc2[0][2]);
        acc2[0][3] = fmaf(x0, w0.w, acc2[0][3]);
        acc2[0][4] = fmaf(x0, w1.x, acc2[0][4]);
        acc2[0][5] = fmaf(x0, w1.y, acc2[0][5]);
        acc2[0][6] = fmaf(x0, w1.z, acc2[0][6]);
        acc2[0][7] = fmaf(x0, w1.w, acc2[0][7]);
        acc2[1][0] = fmaf(x1, w0.x, acc2[1][0]);
        acc2[1][1] = fmaf(x1, w0.y, acc2[1][1]);
        acc2[1][2] = fmaf(x1, w0.z, acc2[1][2]);
        acc2[1][3] = fmaf(x1, w0.w, acc2[1][3]);
        acc2[1][4] = fmaf(x1, w1.x, acc2[1][4]);
        acc2[1][5] = fmaf(x1, w1.y, acc2[1][5]);
        acc2[1][6] = fmaf(x1, w1.z, acc2[1][6]);
        acc2[1][7] = fmaf(x1, w1.w, acc2[1][7]);
    }
#pragma unroll
    for (int r = 0; r < 2; r++) {
        int node = v0 + n0 * 2 + r;
        if (node < N) {
            float d = dinv[node];
            __half2 hh[4];
            hh[0] = __floats2half2_rn(acc2[r][0] * d, acc2[r][1] * d);
            hh[1] = __floats2half2_rn(acc2[r][2] * d, acc2[r][3] * d);
            hh[2] = __floats2half2_rn(acc2[r][4] * d, acc2[r][5] * d);
            hh[3] = __floats2half2_rn(acc2[r][6] * d, acc2[r][7] * d);
            ((int4*)(Q + (size_t)node * 64))[cg] = *(int4*)hh;
        }
    }
}

// ---- layer-2 aggregate + attention pool + projection (Q' pre-scaled fp16) ----
#define GP_NODES 64
__global__ __launch_bounds__(256) void gather_pool_kernel(
    const __half* __restrict__ Q, const int* __restrict__ csr,
    const int* __restrict__ startcnt, const float* __restrict__ dinv,
    const float* __restrict__ bias, const int* __restrict__ batch,
    const float* __restrict__ attn_w, const float* __restrict__ attn_b,
    const float* __restrict__ mask_w, const float* __restrict__ mask_b,
    const float* __restrict__ out_w, float* __restrict__ out, int N) {
    __shared__ float pacc[2048];
    __shared__ int s_gmin, s_span;
    const int tid = threadIdx.x;
    const int v0 = blockIdx.x * GP_NODES;
    const int vend = (v0 + GP_NODES < N) ? v0 + GP_NODES : N;
    if (tid == 0) {
        int gmin = batch[v0];
        s_gmin = gmin;
        s_span = batch[vend - 1] - gmin + 1;
    }
    __syncthreads();
    const int gmin = s_gmin, span = s_span;
    for (int i = tid; i < span; i += 256) pacc[i] = 0.f;
    __syncthreads();

    const int p = tid & 7;          // 8 lanes per fp16 row
    const float4 wa0 = ((const float4*)attn_w)[2 * p], wa1 = ((const float4*)attn_w)[2 * p + 1];
    const float4 wm0 = ((const float4*)mask_w)[2 * p], wm1 = ((const float4*)mask_w)[2 * p + 1];
    const float4 wo0 = ((const float4*)out_w)[2 * p],  wo1 = ((const float4*)out_w)[2 * p + 1];
    const float4 bb0 = ((const float4*)bias)[2 * p],   bb1 = ((const float4*)bias)[2 * p + 1];
    const float ab = attn_b[0], mb = mask_b[0];

    for (int v = v0 + (tid >> 3); v < vend; v += 32) {
        int pack = startcnt[v];
        int st = pack >> 7;
        int c = pack & 127;
        float dv = dinv[v];
        float a[8];
        h8_set(a, ((const int4*)(Q + (size_t)v * 64))[p]);   // self (Q' = dv*Q)
        for (int i = 0; i < c; i += 8) {
            int4 ua = *(const int4*)(csr + st + i);
            int4 ub = *(const int4*)(csr + st + i + 4);
            int4 m0 = ((const int4*)(Q + (size_t)ua.x * 64))[p];
            int4 m1 = ((const int4*)(Q + (size_t)ua.y * 64))[p];
            int4 m2 = ((const int4*)(Q + (size_t)ua.z * 64))[p];
            int4 m3 = ((const int4*)(Q + (size_t)ua.w * 64))[p];
            int4 m4 = ((const int4*)(Q + (size_t)ub.x * 64))[p];
            int4 m5 = ((const int4*)(Q + (size_t)ub.y * 64))[p];
            int4 m6 = ((const int4*)(Q + (size_t)ub.z * 64))[p];
            int4 m7 = ((const int4*)(Q + (size_t)ub.w * 64))[p];
            h8_acc(a, m0);
            if (i + 1 < c) h8_acc(a, m1);
            if (i + 2 < c) h8_acc(a, m2);
            if (i + 3 < c) h8_acc(a, m3);
            if (i + 4 < c) h8_acc(a, m4);
            if (i + 5 < c) h8_acc(a, m5);
            if (i + 6 < c) h8_acc(a, m6);
            if (i + 7 < c) h8_acc(a, m7);
        }
        float h0 = fmaxf(fmaf(a[0], dv, bb0.x), 0.f);
        float h1v = fmaxf(fmaf(a[1], dv, bb0.y), 0.f);
        float h2v = fmaxf(fmaf(a[2], dv, bb0.z), 0.f);
        float h3 = fmaxf(fmaf(a[3], dv, bb0.w), 0.f);
        float h4 = fmaxf(fmaf(a[4], dv, bb1.x), 0.f);
        float h5 = fmaxf(fmaf(a[5], dv, bb1.y), 0.f);
        float h6 = fmaxf(fmaf(a[6], dv, bb1.z), 0.f);
        float h7 = fmaxf(fmaf(a[7], dv, bb1.w), 0.f);
        float pa = h0 * wa0.x + h1v * wa0.y + h2v * wa0.z + h3 * wa0.w
                 + h4 * wa1.x + h5 * wa1.y + h6 * wa1.z + h7 * wa1.w;
        float pm = h0 * wm0.x + h1v * wm0.y + h2v * wm0.z + h3 * wm0.w
                 + h4 * wm1.x + h5 * wm1.y + h6 * wm1.z + h7 * wm1.w;
        float po = h0 * wo0.x + h1v * wo0.y + h2v * wo0.z + h3 * wo0.w
                 + h4 * wo1.x + h5 * wo1.y + h6 * wo1.z + h7 * wo1.w;
#pragma unroll
        for (int off = 1; off < 8; off <<= 1) {   // 8-lane aligned groups
            pa += __shfl_xor(pa, off, 64);
            pm += __shfl_xor(pm, off, 64);
            po += __shfl_xor(po, off, 64);
        }
        if (p == 0) {
            float cc = (pa + ab) * (1.0f / (1.0f + expf(-(pm + mb)))) * po;
            atomicAdd(&pacc[batch[v] - gmin], cc);
        }
    }
    __syncthreads();
    for (int i = tid; i < span; i += 256) {
        float val = pacc[i];
        if (val != 0.f) atomicAdd(&out[gmin + i], val);
    }
}

extern "C" void kernel_launch(void* const* d_in, const int* in_sizes, int n_in,
                              void* d_out, int out_size, void* d_ws, size_t ws_size,
                              hipStream_t stream) {
    const float* x      = (const float*)d_in[0];
    const int*   edge   = (const int*)d_in[1];
    const int*   batch  = (const int*)d_in[2];
    const float* W1     = (const float*)d_in[3];
    const float* b1     = (const float*)d_in[4];
    const float* W2     = (const float*)d_in[5];
    const float* b2     = (const float*)d_in[6];
    const float* attn_w = (const float*)d_in[7];
    const float* attn_b = (const float*)d_in[8];
    const float* mask_w = (const float*)d_in[9];
    const float* mask_b = (const float*)d_in[10];
    const float* out_w  = (const float*)d_in[11];
    const float* out_b  = (const float*)d_in[12];
    float* out = (float*)d_out;

    const int N  = in_sizes[2];
    const int E  = in_sizes[1] / 2;
    const int K1 = in_sizes[0] / N;   // 128
    const int H  = in_sizes[4];       // 64
    const int G  = out_size;          // 2048
    const int* row = edge;            // edge_index[0] = sources
    const int* col = edge + E;        // edge_index[1] = targets

    const int NBUCK = (N + NB - 1) / NB;   // 1563

    // workspace: bcnt 6KB + gbuf 8MB + csr 8MB + startcnt/dinv 0.8MB
    //            + P/Q 2x12.8MB (fp16) ~= 43MB
    char* ws = (char*)d_ws;
    auto align256 = [](size_t s) { return (s + 255) / 256 * 256; };
    int*    bcnt     = (int*)ws;    ws += align256((size_t)NBUCK * 4);
    int*    gbuf     = (int*)ws;    ws += align256((size_t)NBUCK * SLOTS * 4);
    int*    csr      = (int*)ws;    ws += align256((size_t)NBUCK * SLOTS * 4);
    int*    startcnt = (int*)ws;    ws += align256((size_t)N * 4);
    float*  dinv     = (float*)ws;  ws += align256((size_t)N * 4);
    __half* P        = (__half*)ws; ws += align256((size_t)N * H * 2);
    __half* Q        = (__half*)ws;

    const int gblocks = (N + 127) / 128;

    hipMemsetAsync(bcnt, 0, (size_t)NBUCK * 4, stream);
    hipMemsetAsync(csr, 0, (size_t)NBUCK * SLOTS * 4, stream);  // 0-pad for int4 reads

    // fused: block-aggregated two-pass binning (+out init) || P = x@W1 (fp16)
    gemm_bin_kernel<<<BIN_BLOCKS + gblocks, 256, 0, stream>>>(
        x, W1, P, N, K1, row, col, bcnt, gbuf, E, out, out_b, G);

    // per-bucket counting sort -> dense 4-aligned csr + startcnt + dinv
    // + pre-scale P' = dinv * P (bucket-local, coalesced, fp16)
    sort_kernel<<<NBUCK, 256, 0, stream>>>(bcnt, gbuf, csr, startcnt, dinv, P, N);

    // fused layer-1 aggregate (h1 -> LDS) + layer-2 GEMM: Q' = dinv*(h1@W2)
    gather_gemm_kernel<<<NBUCK, 256, 0, stream>>>(
        P, csr, startcnt, dinv, b1, W2, Q, N);

    // layer-2 aggregate + attention pool + projection
    gather_pool_kernel<<<NBUCK, 256, 0, stream>>>(
        Q, csr, startcnt, dinv, b2, batch, attn_w, attn_b, mask_w, mask_b, out_w, out, N);
}

// Round 4
// 237.697 us; speedup vs baseline: 1.0235x; 1.0235x over previous
//
#include <hip/hip_runtime.h>
#include <hip/hip_fp16.h>
#include <math.h>

// ---------------------------------------------------------------------------
// GCN: h1 = relu(Dinv (A+I) Dinv (x@W1) + b1); h2 = relu(Dinv (A+I) Dinv (h1@W2) + b2)
// score = (h2@aw+ab)*sigmoid(h2@mw+mb); out[g] = out_b + sum_v score*(h2@ow)
// R10 sharded bins + counting sort ->277. R12 gather_gemm fusion.
// R13 NEUTRAL (GEMM-loop change): gemm_bin not GEMM-bound.
// R14: fp16 P/Q (fp32 accum) -> gathers -47us (238 total).
// BINNING SCOREBOARD (do not re-derive): R13 per-edge sharded = 65us;
//   R14 x8-batched = 73us; R15 two-pass block-aggregated = ~80us (64-block
//   tail, occupancy 10%). Wide+dumb wins; REVERTED to R13 scheme.
// R16 (this): binning/sort reverted to R13/R14 sharded scheme; NEW:
//   gather_gemm drops the 16KB Wl LDS tile (phase-2 reads W2 direct from
//   global; 16KB shared by all blocks -> L1-resident). LDS 33->16.6KB,
//   4 -> 8 blocks/CU (wave cap) to hide random-gather latency in phase 1.
// ---------------------------------------------------------------------------

#define NB 64              // nodes per bucket (bucket = v >> 6)
#define SEG 16             // counter shards per bucket
#define CAPS 80            // slots per bucket-shard; mean 40, sd 6.3
#define SLOTS (SEG * CAPS) // 1280 slots per bucket
#define BIN_BLOCKS 256

__device__ __forceinline__ void h8_set(float* a, const int4 w) {
    const __half2* h = (const __half2*)&w;
    float2 t0 = __half22float2(h[0]);
    float2 t1 = __half22float2(h[1]);
    float2 t2 = __half22float2(h[2]);
    float2 t3 = __half22float2(h[3]);
    a[0] = t0.x; a[1] = t0.y; a[2] = t1.x; a[3] = t1.y;
    a[4] = t2.x; a[5] = t2.y; a[6] = t3.x; a[7] = t3.y;
}
__device__ __forceinline__ void h8_acc(float* a, const int4 w) {
    const __half2* h = (const __half2*)&w;
    float2 t0 = __half22float2(h[0]);
    float2 t1 = __half22float2(h[1]);
    float2 t2 = __half22float2(h[2]);
    float2 t3 = __half22float2(h[3]);
    a[0] += t0.x; a[1] += t0.y; a[2] += t1.x; a[3] += t1.y;
    a[4] += t2.x; a[5] += t2.y; a[6] += t3.x; a[7] += t3.y;
}

// ---- fused: blocks [0,BIN_BLOCKS) bin edges (+ init out); rest P = x@W1 ----
__global__ __launch_bounds__(256) void gemm_bin_kernel(
    const float* __restrict__ X, const float* __restrict__ W,
    __half* __restrict__ P, int N, int K,
    const int* __restrict__ row, const int* __restrict__ col,
    int* __restrict__ bcnt, int* __restrict__ gbuf, int E,
    float* __restrict__ out, const float* __restrict__ out_b, int G) {
    __shared__ float Wl[32 * 64];    // 8 KB
    __shared__ float xs[32 * 132];   // 16.9 KB TRANSPOSED x tile [k][node]

    if (blockIdx.x < BIN_BLOCKS) {
        // R13-proven wide per-edge sharded binning (65us measured)
        int seg = blockIdx.x & (SEG - 1);
        int t = blockIdx.x * 256 + threadIdx.x;
        if (t < G) out[t] = out_b[0];
        for (int e = t; e < E; e += BIN_BLOCKS * 256) {
            int c = col[e];
            int b = c >> 6;
            // counter padded to its own 64B line: ~40 atomics/line
            int pos = atomicAdd(&bcnt[(b * SEG + seg) * 16], 1);
            if (pos < CAPS) gbuf[b * SLOTS + seg * CAPS + pos] = row[e] | ((c & 63) << 17);
        }
        return;  // uniform per-block branch; never reaches a barrier
    }

    const int tid = threadIdx.x;
    const int cg = tid & 7;        // 8 col-groups x 8 cols
    const int ng = tid >> 3;       // 32 node-groups x 4 rows = 128 nodes
    const int node0 = (blockIdx.x - BIN_BLOCKS) * 128;

    float acc[4][8];
#pragma unroll
    for (int r = 0; r < 4; r++)
#pragma unroll
        for (int j = 0; j < 8; j++) acc[r][j] = 0.0f;

    for (int k0 = 0; k0 < K; k0 += 32) {   // runtime loop: keeps VGPR bounded
        const float4* Wg = (const float4*)(W + (size_t)k0 * 64);
#pragma unroll
        for (int f = tid; f < 512; f += 256) ((float4*)Wl)[f] = Wg[f];
        {
            int rrow = tid >> 1;
            int q0 = (tid & 1) * 16;
            int node = node0 + rrow;
            const float* Xr = X + (size_t)node * K + k0 + q0;
#pragma unroll
            for (int q = 0; q < 4; q++) {
                float4 v = make_float4(0.f, 0.f, 0.f, 0.f);
                if (node < N) v = *(const float4*)(Xr + 4 * q);
                int kb = q0 + 4 * q;           // transposed store: xs[k][node]
                xs[(kb + 0) * 132 + rrow] = v.x;
                xs[(kb + 1) * 132 + rrow] = v.y;
                xs[(kb + 2) * 132 + rrow] = v.z;
                xs[(kb + 3) * 132 + rrow] = v.w;
            }
        }
        __syncthreads();
#pragma unroll
        for (int kk = 0; kk < 32; kk++) {
            float4 xv = *(const float4*)&xs[kk * 132 + ng * 4];
            const float* wr = &Wl[kk * 64 + cg * 8];
            float4 w0 = *(const float4*)(wr + 0);
            float4 w1 = *(const float4*)(wr + 4);
#pragma unroll
            for (int r = 0; r < 4; r++) {
                float xr = (r == 0) ? xv.x : (r == 1) ? xv.y : (r == 2) ? xv.z : xv.w;
                acc[r][0] = fmaf(xr, w0.x, acc[r][0]);
                acc[r][1] = fmaf(xr, w0.y, acc[r][1]);
                acc[r][2] = fmaf(xr, w0.z, acc[r][2]);
                acc[r][3] = fmaf(xr, w0.w, acc[r][3]);
                acc[r][4] = fmaf(xr, w1.x, acc[r][4]);
                acc[r][5] = fmaf(xr, w1.y, acc[r][5]);
                acc[r][6] = fmaf(xr, w1.z, acc[r][6]);
                acc[r][7] = fmaf(xr, w1.w, acc[r][7]);
            }
        }
        __syncthreads();
    }

#pragma unroll
    for (int r = 0; r < 4; r++) {
        int node = node0 + ng * 4 + r;
        if (node < N) {
            __half2 hh[4];
            hh[0] = __floats2half2_rn(acc[r][0], acc[r][1]);
            hh[1] = __floats2half2_rn(acc[r][2], acc[r][3]);
            hh[2] = __floats2half2_rn(acc[r][4], acc[r][5]);
            hh[3] = __floats2half2_rn(acc[r][6], acc[r][7]);
            ((int4*)(P + (size_t)node * 64))[cg] = *(int4*)hh;
        }
    }
}

// ---- per-bucket LDS counting sort: gbuf segments -> dense node-ordered csr
//      (4-aligned per-node regions, pre-zeroed pad), writes dinv + packed
//      startcnt, then pre-scales P' = dinv * P (fp16 rows, coalesced) ----
__global__ __launch_bounds__(256) void sort_kernel(
    const int* __restrict__ bcnt, const int* __restrict__ gbuf,
    int* __restrict__ csr, int* __restrict__ startcnt,
    float* __restrict__ dinv, __half* __restrict__ P, int N) {
    __shared__ int scnt[SEG], segoff[SEG], s_tot;
    __shared__ int ebuf[SLOTS];     // 5 KB
    __shared__ int lcnt[NB], lcur[NB];
    __shared__ float sdinv[NB];
    const int tid = threadIdx.x;
    const int b = blockIdx.x;
    const int base = b * SLOTS;

    if (tid < SEG) {
        int c = bcnt[(b * SEG + tid) * 16];
        scnt[tid] = c < CAPS ? c : CAPS;
    }
    if (tid < NB) lcnt[tid] = 0;
    __syncthreads();
    if (tid == 0) {
        int o = 0;
        for (int s = 0; s < SEG; s++) { segoff[s] = o; o += scnt[s]; }
        s_tot = o;
    }
    __syncthreads();
    for (int idx = tid; idx < SLOTS; idx += 256) {
        int seg = idx / CAPS;
        int j = idx - seg * CAPS;
        if (j < scnt[seg]) {
            int w = gbuf[base + idx];
            ebuf[segoff[seg] + j] = w;
            atomicAdd(&lcnt[(w >> 17) & 63], 1);
        }
    }
    __syncthreads();
    if (tid < NB) {
        int cntv = lcnt[tid];
        int rnd = (cntv + 3) & ~3;          // 4-aligned region for int4 loads
        int val = rnd;
#pragma unroll
        for (int off = 1; off < 64; off <<= 1) {
            int n = __shfl_up(val, off, 64);
            if (tid >= off) val += n;
        }
        int st = val - rnd;
        lcur[tid] = st;
        float d = rsqrtf(1.0f + (float)cntv);
        sdinv[tid] = d;
        int v = b * NB + tid;
        if (v < N) {
            dinv[v] = d;
            int cc = cntv < 127 ? cntv : 127;
            startcnt[v] = ((base + st) << 7) | cc;   // base+st < 2M -> fits
        }
    }
    __syncthreads();
    int tot = s_tot;
    for (int idx = tid; idx < tot; idx += 256) {
        int w = ebuf[idx];
        int vl = (w >> 17) & 63;
        int pp = atomicAdd(&lcur[vl], 1);
        csr[base + pp] = w & 131071;
    }
    // pre-scale this bucket's fp16 P rows: P'[v] = dinv[v] * P[v]
    for (int idx = tid; idx < NB * 8; idx += 256) {   // 8x16B chunks per row
        int r = idx >> 3;
        int v = b * NB + r;
        if (v < N) {
            float d = sdinv[r];
            int4* pp = (int4*)(P + (size_t)v * 64) + (idx & 7);
            int4 t = *pp;
            __half2* hp = (__half2*)&t;
#pragma unroll
            for (int q = 0; q < 4; q++) {
                float2 f = __half22float2(hp[q]);
                hp[q] = __floats2half2_rn(f.x * d, f.y * d);
            }
            *pp = t;
        }
    }
}

// ---- fused layer-1 aggregate + layer-2 GEMM ----
// Block = 64 nodes (one bucket). Phase 1: gather fp16 P' rows (8 lanes/row,
// int4/lane) -> fp32 accum -> h1 tile in LDS. Phase 2: Q' = dinv*(h1@W2),
// 2x8 register tile, RUNTIME kk-loop, W2 read DIRECT from global (16KB,
// shared by all blocks -> L1-resident). LDS 16.6KB -> 8 blocks/CU (wave cap).
__global__ __launch_bounds__(256) void gather_gemm_kernel(
    const __half* __restrict__ P, const int* __restrict__ csr,
    const int* __restrict__ startcnt, const float* __restrict__ dinv,
    const float* __restrict__ b1, const float* __restrict__ W2,
    __half* __restrict__ Q, int N) {
    __shared__ float hs[64 * 65];   // 16.6 KB h1 tile (only LDS)
    const int tid = threadIdx.x;
    const int v0 = blockIdx.x * 64;
    const int vend = (v0 + 64 < N) ? v0 + 64 : N;
    const int p = tid & 7;          // 8 lanes per row (128B fp16 row)

    const float4 bb0 = ((const float4*)b1)[2 * p];
    const float4 bb1 = ((const float4*)b1)[2 * p + 1];
    for (int v = v0 + (tid >> 3); v < vend; v += 32) {
        int pack = startcnt[v];
        int st = pack >> 7;           // 4-aligned
        int c = pack & 127;
        float dv = dinv[v];
        float a[8];
        h8_set(a, ((const int4*)(P + (size_t)v * 64))[p]);   // self: P' has dv
        for (int i = 0; i < c; i += 8) {
            int4 ua = *(const int4*)(csr + st + i);      // pad slots = 0, safe
            int4 ub = *(const int4*)(csr + st + i + 4);
            int4 m0 = ((const int4*)(P + (size_t)ua.x * 64))[p];
            int4 m1 = ((const int4*)(P + (size_t)ua.y * 64))[p];
            int4 m2 = ((const int4*)(P + (size_t)ua.z * 64))[p];
            int4 m3 = ((const int4*)(P + (size_t)ua.w * 64))[p];
            int4 m4 = ((const int4*)(P + (size_t)ub.x * 64))[p];
            int4 m5 = ((const int4*)(P + (size_t)ub.y * 64))[p];
            int4 m6 = ((const int4*)(P + (size_t)ub.z * 64))[p];
            int4 m7 = ((const int4*)(P + (size_t)ub.w * 64))[p];
            h8_acc(a, m0);
            if (i + 1 < c) h8_acc(a, m1);
            if (i + 2 < c) h8_acc(a, m2);
            if (i + 3 < c) h8_acc(a, m3);
            if (i + 4 < c) h8_acc(a, m4);
            if (i + 5 < c) h8_acc(a, m5);
            if (i + 6 < c) h8_acc(a, m6);
            if (i + 7 < c) h8_acc(a, m7);
        }
        float* hd = &hs[(v - v0) * 65 + p * 8];
        hd[0] = fmaxf(fmaf(a[0], dv, bb0.x), 0.f);
        hd[1] = fmaxf(fmaf(a[1], dv, bb0.y), 0.f);
        hd[2] = fmaxf(fmaf(a[2], dv, bb0.z), 0.f);
        hd[3] = fmaxf(fmaf(a[3], dv, bb0.w), 0.f);
        hd[4] = fmaxf(fmaf(a[4], dv, bb1.x), 0.f);
        hd[5] = fmaxf(fmaf(a[5], dv, bb1.y), 0.f);
        hd[6] = fmaxf(fmaf(a[6], dv, bb1.z), 0.f);
        hd[7] = fmaxf(fmaf(a[7], dv, bb1.w), 0.f);
    }
    __syncthreads();

    // Phase 2: Q'[v] = dinv * (hs @ W2); 2 rows x 8 cols per thread;
    // W2 from global (L1-hot: every block reads the same 16KB)
    const int cg = tid & 7;
    const int n0 = tid >> 3;       // 0..31, 2 rows each
    float acc2[2][8];
#pragma unroll
    for (int r = 0; r < 2; r++)
#pragma unroll
        for (int j = 0; j < 8; j++) acc2[r][j] = 0.0f;
    for (int kk = 0; kk < 64; kk++) {     // RUNTIME loop (R6/R8 lesson)
        float x0 = hs[(n0 * 2 + 0) * 65 + kk];
        float x1 = hs[(n0 * 2 + 1) * 65 + kk];
        const float* wr = W2 + kk * 64 + cg * 8;
        float4 w0 = *(const float4*)(wr + 0);
        float4 w1 = *(const float4*)(wr + 4);
        acc2[0][0] = fmaf(x0, w0.x, acc2[0][0]);
        acc2[0][1] = fmaf(x0, w0.y, acc2[0][1]);
        acc2[0][2] = fmaf(x0, w0.z, acc2[0][2]);
        acc2[0][3] = fmaf(x0, w0.w, acc2[0][3]);
        acc2[0][4] = fmaf(x0, w1.x, acc2[0][4]);
        acc2[0][5] = fmaf(x0, w1.y, acc2[0][5]);
        acc2[0][6] = fmaf(x0, w1.z, acc2[0][6]);
        acc2[0][7] = fmaf(x0, w1.w, acc2[0][7]);
        acc2[1][0] = fmaf(x1, w0.x, acc2[1][0]);
        acc2[1][1] = fmaf(x1, w0.y, acc2[1][1]);
        acc2[1][2] = fmaf(x1, w0.z, acc2[1][2]);
        acc2[1][3] = fmaf(x1, w0.w, acc2[1][3]);
        acc2[1][4] = fmaf(x1, w1.x, acc2[1][4]);
        acc2[1][5] = fmaf(x1, w1.y, acc2[1][5]);
        acc2[1][6] = fmaf(x1, w1.z, acc2[1][6]);
        acc2[1][7] = fmaf(x1, w1.w, acc2[1][7]);
    }
#pragma unroll
    for (int r = 0; r < 2; r++) {
        int node = v0 + n0 * 2 + r;
        if (node < N) {
            float d = dinv[node];
            __half2 hh[4];
            hh[0] = __floats2half2_rn(acc2[r][0] * d, acc2[r][1] * d);
            hh[1] = __floats2half2_rn(acc2[r][2] * d, acc2[r][3] * d);
            hh[2] = __floats2half2_rn(acc2[r][4] * d, acc2[r][5] * d);
            hh[3] = __floats2half2_rn(acc2[r][6] * d, acc2[r][7] * d);
            ((int4*)(Q + (size_t)node * 64))[cg] = *(int4*)hh;
        }
    }
}

// ---- layer-2 aggregate + attention pool + projection (Q' pre-scaled fp16) ----
#define GP_NODES 64
__global__ __launch_bounds__(256) void gather_pool_kernel(
    const __half* __restrict__ Q, const int* __restrict__ csr,
    const int* __restrict__ startcnt, const float* __restrict__ dinv,
    const float* __restrict__ bias, const int* __restrict__ batch,
    const float* __restrict__ attn_w, const float* __restrict__ attn_b,
    const float* __restrict__ mask_w, const float* __restrict__ mask_b,
    const float* __restrict__ out_w, float* __restrict__ out, int N) {
    __shared__ float pacc[2048];
    __shared__ int s_gmin, s_span;
    const int tid = threadIdx.x;
    const int v0 = blockIdx.x * GP_NODES;
    const int vend = (v0 + GP_NODES < N) ? v0 + GP_NODES : N;
    if (tid == 0) {
        int gmin = batch[v0];
        s_gmin = gmin;
        s_span = batch[vend - 1] - gmin + 1;
    }
    __syncthreads();
    const int gmin = s_gmin, span = s_span;
    for (int i = tid; i < span; i += 256) pacc[i] = 0.f;
    __syncthreads();

    const int p = tid & 7;          // 8 lanes per fp16 row
    const float4 wa0 = ((const float4*)attn_w)[2 * p], wa1 = ((const float4*)attn_w)[2 * p + 1];
    const float4 wm0 = ((const float4*)mask_w)[2 * p], wm1 = ((const float4*)mask_w)[2 * p + 1];
    const float4 wo0 = ((const float4*)out_w)[2 * p],  wo1 = ((const float4*)out_w)[2 * p + 1];
    const float4 bb0 = ((const float4*)bias)[2 * p],   bb1 = ((const float4*)bias)[2 * p + 1];
    const float ab = attn_b[0], mb = mask_b[0];

    for (int v = v0 + (tid >> 3); v < vend; v += 32) {
        int pack = startcnt[v];
        int st = pack >> 7;
        int c = pack & 127;
        float dv = dinv[v];
        float a[8];
        h8_set(a, ((const int4*)(Q + (size_t)v * 64))[p]);   // self (Q' = dv*Q)
        for (int i = 0; i < c; i += 8) {
            int4 ua = *(const int4*)(csr + st + i);
            int4 ub = *(const int4*)(csr + st + i + 4);
            int4 m0 = ((const int4*)(Q + (size_t)ua.x * 64))[p];
            int4 m1 = ((const int4*)(Q + (size_t)ua.y * 64))[p];
            int4 m2 = ((const int4*)(Q + (size_t)ua.z * 64))[p];
            int4 m3 = ((const int4*)(Q + (size_t)ua.w * 64))[p];
            int4 m4 = ((const int4*)(Q + (size_t)ub.x * 64))[p];
            int4 m5 = ((const int4*)(Q + (size_t)ub.y * 64))[p];
            int4 m6 = ((const int4*)(Q + (size_t)ub.z * 64))[p];
            int4 m7 = ((const int4*)(Q + (size_t)ub.w * 64))[p];
            h8_acc(a, m0);
            if (i + 1 < c) h8_acc(a, m1);
            if (i + 2 < c) h8_acc(a, m2);
            if (i + 3 < c) h8_acc(a, m3);
            if (i + 4 < c) h8_acc(a, m4);
            if (i + 5 < c) h8_acc(a, m5);
            if (i + 6 < c) h8_acc(a, m6);
            if (i + 7 < c) h8_acc(a, m7);
        }
        float h0 = fmaxf(fmaf(a[0], dv, bb0.x), 0.f);
        float h1v = fmaxf(fmaf(a[1], dv, bb0.y), 0.f);
        float h2v = fmaxf(fmaf(a[2], dv, bb0.z), 0.f);
        float h3 = fmaxf(fmaf(a[3], dv, bb0.w), 0.f);
        float h4 = fmaxf(fmaf(a[4], dv, bb1.x), 0.f);
        float h5 = fmaxf(fmaf(a[5], dv, bb1.y), 0.f);
        float h6 = fmaxf(fmaf(a[6], dv, bb1.z), 0.f);
        float h7 = fmaxf(fmaf(a[7], dv, bb1.w), 0.f);
        float pa = h0 * wa0.x + h1v * wa0.y + h2v * wa0.z + h3 * wa0.w
                 + h4 * wa1.x + h5 * wa1.y + h6 * wa1.z + h7 * wa1.w;
        float pm = h0 * wm0.x + h1v * wm0.y + h2v * wm0.z + h3 * wm0.w
                 + h4 * wm1.x + h5 * wm1.y + h6 * wm1.z + h7 * wm1.w;
        float po = h0 * wo0.x + h1v * wo0.y + h2v * wo0.z + h3 * wo0.w
                 + h4 * wo1.x + h5 * wo1.y + h6 * wo1.z + h7 * wo1.w;
#pragma unroll
        for (int off = 1; off < 8; off <<= 1) {   // 8-lane aligned groups
            pa += __shfl_xor(pa, off, 64);
            pm += __shfl_xor(pm, off, 64);
            po += __shfl_xor(po, off, 64);
        }
        if (p == 0) {
            float cc = (pa + ab) * (1.0f / (1.0f + expf(-(pm + mb)))) * po;
            atomicAdd(&pacc[batch[v] - gmin], cc);
        }
    }
    __syncthreads();
    for (int i = tid; i < span; i += 256) {
        float val = pacc[i];
        if (val != 0.f) atomicAdd(&out[gmin + i], val);
    }
}

extern "C" void kernel_launch(void* const* d_in, const int* in_sizes, int n_in,
                              void* d_out, int out_size, void* d_ws, size_t ws_size,
                              hipStream_t stream) {
    const float* x      = (const float*)d_in[0];
    const int*   edge   = (const int*)d_in[1];
    const int*   batch  = (const int*)d_in[2];
    const float* W1     = (const float*)d_in[3];
    const float* b1     = (const float*)d_in[4];
    const float* W2     = (const float*)d_in[5];
    const float* b2     = (const float*)d_in[6];
    const float* attn_w = (const float*)d_in[7];
    const float* attn_b = (const float*)d_in[8];
    const float* mask_w = (const float*)d_in[9];
    const float* mask_b = (const float*)d_in[10];
    const float* out_w  = (const float*)d_in[11];
    const float* out_b  = (const float*)d_in[12];
    float* out = (float*)d_out;

    const int N  = in_sizes[2];
    const int E  = in_sizes[1] / 2;
    const int K1 = in_sizes[0] / N;   // 128
    const int H  = in_sizes[4];       // 64
    const int G  = out_size;          // 2048
    const int* row = edge;            // edge_index[0] = sources
    const int* col = edge + E;        // edge_index[1] = targets

    const int NBUCK = (N + NB - 1) / NB;   // 1563

    // workspace: bcnt 1.6MB + gbuf 8MB + csr 8MB + startcnt/dinv 0.8MB
    //            + P/Q 2x12.8MB (fp16) ~= 44MB
    char* ws = (char*)d_ws;
    auto align256 = [](size_t s) { return (s + 255) / 256 * 256; };
    int*    bcnt     = (int*)ws;    ws += align256((size_t)NBUCK * SEG * 16 * 4);
    int*    gbuf     = (int*)ws;    ws += align256((size_t)NBUCK * SLOTS * 4);
    int*    csr      = (int*)ws;    ws += align256((size_t)NBUCK * SLOTS * 4);
    int*    startcnt = (int*)ws;    ws += align256((size_t)N * 4);
    float*  dinv     = (float*)ws;  ws += align256((size_t)N * 4);
    __half* P        = (__half*)ws; ws += align256((size_t)N * H * 2);
    __half* Q        = (__half*)ws;

    const int gblocks = (N + 127) / 128;

    hipMemsetAsync(bcnt, 0, (size_t)NBUCK * SEG * 16 * 4, stream);
    hipMemsetAsync(csr, 0, (size_t)NBUCK * SLOTS * 4, stream);  // 0-pad for int4 reads

    // fused: sharded per-edge binning (+out init) || P = x@W1 (fp16 out)
    gemm_bin_kernel<<<BIN_BLOCKS + gblocks, 256, 0, stream>>>(
        x, W1, P, N, K1, row, col, bcnt, gbuf, E, out, out_b, G);

    // per-bucket counting sort -> dense 4-aligned csr + startcnt + dinv
    // + pre-scale P' = dinv * P (bucket-local, coalesced, fp16)
    sort_kernel<<<NBUCK, 256, 0, stream>>>(bcnt, gbuf, csr, startcnt, dinv, P, N);

    // fused layer-1 aggregate (h1 -> LDS) + layer-2 GEMM: Q' = dinv*(h1@W2)
    gather_gemm_kernel<<<NBUCK, 256, 0, stream>>>(
        P, csr, startcnt, dinv, b1, W2, Q, N);

    // layer-2 aggregate + attention pool + projection
    gather_pool_kernel<<<NBUCK, 256, 0, stream>>>(
        Q, csr, startcnt, dinv, b2, batch, attn_w, attn_b, mask_w, mask_b, out_w, out, N);
}